// Round 1
// baseline (2005.974 us; speedup 1.0000x reference)
//
#include <hip/hip_runtime.h>
#include <hip/hip_bf16.h>

#define TB 256

// Tree geometry (branch=8, depth=6) — hardcoded per reference scalars.
// Level l: n_l = 8^l nodes at global offset off(l) = (8^l - 1)/7.
// Children of (level l, local p) are level l+1 locals [8p, 8p+8).

__device__ __forceinline__ float sigm(float v){ return 1.0f/(1.0f + __expf(-v)); }

// Stage a 128x128 chunk of W (rows krow0..krow0+127, row-major [*,128]) into
// LDS [128][132] (pad 132 keeps float4 alignment; inner-loop reads are ~4-way
// bank conflicted which is the floor for b128 row-gather).
__device__ __forceinline__ void stage_w128(const float* __restrict__ W, int krow0,
                                           float (*Wt)[132], int tid){
  #pragma unroll 4
  for (int idx = tid; idx < 128*128; idx += TB){
    int kk = idx >> 7, mm = idx & 127;
    Wt[kk][mm] = W[(krow0 + kk)*128 + mm];
  }
}

// acc[i][j] += dot(A row (rg*4+j), cols [m0,m0+128), Wt row (kg+32i))
// 256 threads: rg = tid>>5 (8 row groups x 4 rows), kg = tid&31 (k = kg+32i).
__device__ __forceinline__ void gemm_pass(const float* __restrict__ At, int lda, int m0,
                                          const float (*Wt)[132], int rg, int kg,
                                          float acc[4][4]){
  #pragma unroll 4
  for (int m4 = 0; m4 < 32; ++m4){
    float4 a[4], w[4];
    #pragma unroll
    for (int j = 0; j < 4; ++j)
      a[j] = *reinterpret_cast<const float4*>(At + (rg*4 + j)*lda + m0 + m4*4);
    #pragma unroll
    for (int i = 0; i < 4; ++i)
      w[i] = *reinterpret_cast<const float4*>(&Wt[kg + 32*i][m4*4]);
    #pragma unroll
    for (int i = 0; i < 4; ++i)
      #pragma unroll
      for (int j = 0; j < 4; ++j)
        acc[i][j] += a[j].x*w[i].x + a[j].y*w[i].y + a[j].z*w[i].z + a[j].w*w[i].w;
  }
}

// FX[l] = X_l @ W_fx^T + b_fx    (per-level parents; N=128, K=128)
__global__ __launch_bounds__(TB)
void k_fx(const float* __restrict__ x, const float* __restrict__ Wfx,
          const float* __restrict__ bfx, float* __restrict__ FX,
          int node_off, int nrows){
  __shared__ float At[32][128];
  __shared__ float Wt[128][132];
  const int tid = threadIdx.x, rg = tid >> 5, kg = tid & 31;
  const int mbase = blockIdx.x * 32;

  #pragma unroll 4
  for (int idx = tid; idx < 32*128; idx += TB){
    int row = idx >> 7, m = idx & 127;
    int gr = min(mbase + row, nrows - 1);
    At[row][m] = x[(size_t)(node_off + gr)*128 + m];
  }
  stage_w128(Wfx, 0, Wt, tid);
  __syncthreads();

  float acc[4][4] = {};
  gemm_pass(&At[0][0], 128, 0, Wt, rg, kg, acc);

  #pragma unroll
  for (int i = 0; i < 4; ++i){
    int k = kg + 32*i;
    #pragma unroll
    for (int j = 0; j < 4; ++j){
      int gr = mbase + rg*4 + j;
      if (gr < nrows) FX[(size_t)gr*128 + k] = acc[i][j] + bfx[k];
    }
  }
}

// Fused leaf + FH for level 5: block owns 32 leaves (= 4 level-5 parents).
// Phase A: leaf iou -> c,h in LDS.  Phase B: FH = h @ W_fh^T, f-gate, and
// per-parent reductions -> hsum, fcsum (level-5 local indexing).
__global__ __launch_bounds__(TB)
void k_leaf(const float* __restrict__ x,
            const float* __restrict__ Wioux, const float* __restrict__ bioux,
            const float* __restrict__ biouh,
            const float* __restrict__ Wfh, const float* __restrict__ bfh,
            const float* __restrict__ FX,
            float* __restrict__ hsum, float* __restrict__ fcsum,
            int leaf_off, int nleaves){
  __shared__ float At[32][128];     // leaf x rows; reused as f*c scratch
  __shared__ float Wt[128][132];
  __shared__ float ct[32][132];
  __shared__ float ht[32][132];
  const int tid = threadIdx.x, rg = tid >> 5, kg = tid & 31;
  const int mbase = blockIdx.x * 32;   // nleaves % 32 == 0

  #pragma unroll 4
  for (int idx = tid; idx < 32*128; idx += TB){
    int row = idx >> 7, m = idx & 127;
    int gr = min(mbase + row, nleaves - 1);
    At[row][m] = x[(size_t)(leaf_off + gr)*128 + m];
  }

  float acc[3][4][4] = {};
  #pragma unroll
  for (int kt = 0; kt < 3; ++kt){
    __syncthreads();                  // protect Wt from previous pass
    stage_w128(Wioux, kt*128, Wt, tid);
    __syncthreads();
    gemm_pass(&At[0][0], 128, 0, Wt, rg, kg, acc[kt]);
  }

  // leaf gates: h_sum = 0 -> iou = x@Wioux^T + b_ioux + b_iouh ; fc_sum = 0
  #pragma unroll
  for (int i = 0; i < 4; ++i){
    int k = kg + 32*i;
    #pragma unroll
    for (int j = 0; j < 4; ++j){
      int row = rg*4 + j;
      float iv = acc[0][i][j] + bioux[k]       + biouh[k];
      float ov = acc[1][i][j] + bioux[128 + k] + biouh[128 + k];
      float uv = acc[2][i][j] + bioux[256 + k] + biouh[256 + k];
      float c = sigm(iv) * tanhf(uv);
      float h = sigm(ov) * tanhf(c);
      ct[row][k] = c; ht[row][k] = h;
    }
  }
  __syncthreads();

  // Phase B: FH = ht @ Wfh^T
  stage_w128(Wfh, 0, Wt, tid);
  __syncthreads();
  float fa[4][4] = {};
  gemm_pass(&ht[0][0], 132, 0, Wt, rg, kg, fa);

  // f-gate, f*c into At (safe: every thread finished reading At before the
  // last barrier; each thread writes only after its own pass completes and
  // all other threads' reads of At ended at the barrier above)
  #pragma unroll
  for (int i = 0; i < 4; ++i){
    int k = kg + 32*i;
    #pragma unroll
    for (int j = 0; j < 4; ++j){
      int row = rg*4 + j;
      int p = (mbase + row) >> 3;           // level-5 local parent
      float f = sigm(fa[i][j] + bfh[k] + FX[(size_t)p*128 + k]);
      At[row][k] = f * ct[row][k];
    }
  }
  __syncthreads();

  // reductions: 4 parents x 128 k
  for (int idx = tid; idx < 512; idx += TB){
    int pl = idx >> 7, k = idx & 127;
    float fs = 0.f, hs = 0.f;
    #pragma unroll
    for (int b = 0; b < 8; ++b){ fs += At[pl*8 + b][k]; hs += ht[pl*8 + b][k]; }
    int gp = (mbase >> 3) + pl;
    fcsum[(size_t)gp*128 + k] = fs;
    hsum [(size_t)gp*128 + k] = hs;
  }
}

// FH for internal levels (children c,h from f32 ws buffers) -> hsum, fcsum
__global__ __launch_bounds__(TB)
void k_fh(const float* __restrict__ c_ch, const float* __restrict__ h_ch,
          const float* __restrict__ Wfh, const float* __restrict__ bfh,
          const float* __restrict__ FX,
          float* __restrict__ hsum, float* __restrict__ fcsum,
          int nch, int npar){
  __shared__ float At[32][128];     // child h rows
  __shared__ float Wt[128][132];
  __shared__ float red[32][128];
  const int tid = threadIdx.x, rg = tid >> 5, kg = tid & 31;
  const int mbase = blockIdx.x * 32;

  #pragma unroll 4
  for (int idx = tid; idx < 32*128; idx += TB){
    int row = idx >> 7, m = idx & 127;
    int gr = min(mbase + row, nch - 1);
    At[row][m] = h_ch[(size_t)gr*128 + m];
  }
  stage_w128(Wfh, 0, Wt, tid);
  __syncthreads();

  float fa[4][4] = {};
  gemm_pass(&At[0][0], 128, 0, Wt, rg, kg, fa);

  #pragma unroll
  for (int i = 0; i < 4; ++i){
    int k = kg + 32*i;
    #pragma unroll
    for (int j = 0; j < 4; ++j){
      int row = rg*4 + j;
      int cl = min(mbase + row, nch - 1);
      int p = cl >> 3;
      float f = sigm(fa[i][j] + bfh[k] + FX[(size_t)p*128 + k]);
      red[row][k] = f * c_ch[(size_t)cl*128 + k];
    }
  }
  __syncthreads();

  for (int idx = tid; idx < 512; idx += TB){
    int pl = idx >> 7, k = idx & 127;
    float fs = 0.f, hs = 0.f;
    #pragma unroll
    for (int b = 0; b < 8; ++b){ fs += red[pl*8 + b][k]; hs += At[pl*8 + b][k]; }
    int gp = (mbase >> 3) + pl;
    if (gp < npar){
      fcsum[(size_t)gp*128 + k] = fs;
      hsum [(size_t)gp*128 + k] = hs;
    }
  }
}

// IOU = [X_l | H_sum] @ [W_ioux | W_iouh]^T + biases ; gates -> c,h (+root out)
__global__ __launch_bounds__(TB)
void k_iou(const float* __restrict__ x, const float* __restrict__ hsum,
           const float* __restrict__ Wioux, const float* __restrict__ bioux,
           const float* __restrict__ Wiouh, const float* __restrict__ biouh,
           const float* __restrict__ fcsum,
           float* __restrict__ c_out, float* __restrict__ h_out,
           float* __restrict__ dout,
           int node_off, int nrows){
  __shared__ float At[32][256];
  __shared__ float Wt[128][132];
  const int tid = threadIdx.x, rg = tid >> 5, kg = tid & 31;
  const int mbase = blockIdx.x * 32;

  #pragma unroll 4
  for (int idx = tid; idx < 32*256; idx += TB){
    int row = idx >> 8, m = idx & 255;
    int gr = min(mbase + row, nrows - 1);
    At[row][m] = (m < 128) ? x[(size_t)(node_off + gr)*128 + m]
                           : hsum[(size_t)gr*128 + (m - 128)];
  }

  float acc[3][4][4] = {};
  #pragma unroll
  for (int kt = 0; kt < 3; ++kt){
    #pragma unroll
    for (int kh = 0; kh < 2; ++kh){
      __syncthreads();
      stage_w128(kh ? Wiouh : Wioux, kt*128, Wt, tid);
      __syncthreads();
      gemm_pass(&At[0][0], 256, kh*128, Wt, rg, kg, acc[kt]);
    }
  }

  #pragma unroll
  for (int i = 0; i < 4; ++i){
    int k = kg + 32*i;
    #pragma unroll
    for (int j = 0; j < 4; ++j){
      int gr = mbase + rg*4 + j;
      int grc = min(gr, nrows - 1);
      float iv = acc[0][i][j] + bioux[k]       + biouh[k];
      float ov = acc[1][i][j] + bioux[128 + k] + biouh[128 + k];
      float uv = acc[2][i][j] + bioux[256 + k] + biouh[256 + k];
      float c = sigm(iv) * tanhf(uv) + fcsum[(size_t)grc*128 + k];
      float h = sigm(ov) * tanhf(c);
      if (gr < nrows){
        c_out[(size_t)gr*128 + k] = c;
        h_out[(size_t)gr*128 + k] = h;
        if (dout && gr == 0){ dout[k] = c; dout[128 + k] = h; }
      }
    }
  }
}

extern "C" void kernel_launch(void* const* d_in, const int* in_sizes, int n_in,
                              void* d_out, int out_size, void* d_ws, size_t ws_size,
                              hipStream_t stream) {
  const float* x     = (const float*)d_in[0];
  const float* Wioux = (const float*)d_in[1];
  const float* bioux = (const float*)d_in[2];
  const float* Wiouh = (const float*)d_in[3];
  const float* biouh = (const float*)d_in[4];
  const float* Wfx   = (const float*)d_in[5];
  const float* bfx   = (const float*)d_in[6];
  const float* Wfh   = (const float*)d_in[7];
  const float* bfh   = (const float*)d_in[8];
  float* dout = (float*)d_out;

  static const int n_l[7]  = {1, 8, 64, 512, 4096, 32768, 262144};
  static const int off_l[7] = {0, 1, 9, 73, 585, 4681, 37449};

  // ws layout (floats): FX | HS | FC | Xc | Xh | Yc | Yh
  const size_t L5 = (size_t)32768 * 128;
  const size_t L4 = (size_t)4096 * 128;
  const size_t need = (6*L5 + 2*L4) * sizeof(float);   // ~100 MB
  if (ws_size < need) return;   // ws too small -> clean zero-output failure signal

  float* FX = (float*)d_ws;
  float* HS = FX + L5;
  float* FC = HS + L5;
  float* Xc = FC + L5;
  float* Xh = Xc + L5;
  float* Yc = Xh + L5;
  float* Yh = Yc + L4;

  dim3 blk(TB);

  // level 5 (children = leaves, fused)
  k_fx  <<<n_l[5]/32, blk, 0, stream>>>(x, Wfx, bfx, FX, off_l[5], n_l[5]);
  k_leaf<<<n_l[6]/32, blk, 0, stream>>>(x, Wioux, bioux, biouh, Wfh, bfh, FX,
                                        HS, FC, off_l[6], n_l[6]);
  k_iou <<<n_l[5]/32, blk, 0, stream>>>(x, HS, Wioux, bioux, Wiouh, biouh, FC,
                                        Xc, Xh, nullptr, off_l[5], n_l[5]);

  for (int l = 4; l >= 0; --l){
    int nl = n_l[l], nch = n_l[l+1], offl = off_l[l];
    const float* cin = (l % 2 == 0) ? Xc : Yc;
    const float* hin = (l % 2 == 0) ? Xh : Yh;
    float* co = (l % 2 == 0) ? Yc : Xc;
    float* ho = (l % 2 == 0) ? Yh : Xh;
    k_fx <<<(nl  + 31)/32, blk, 0, stream>>>(x, Wfx, bfx, FX, offl, nl);
    k_fh <<<(nch + 31)/32, blk, 0, stream>>>(cin, hin, Wfh, bfh, FX, HS, FC, nch, nl);
    k_iou<<<(nl  + 31)/32, blk, 0, stream>>>(x, HS, Wioux, bioux, Wiouh, biouh, FC,
                                             co, ho, (l == 0) ? dout : nullptr, offl, nl);
  }
}

// Round 2
// 638.970 us; speedup vs baseline: 3.1394x; 3.1394x over previous
//
#include <hip/hip_runtime.h>
#include <hip/hip_bf16.h>

#define TB 256

typedef __attribute__((ext_vector_type(8))) short bf16x8;
typedef __attribute__((ext_vector_type(4))) float f32x4;

__device__ __forceinline__ float sigm(float v){ return 1.0f/(1.0f+__expf(-v)); }

// f32 -> bf16 bits, round-to-nearest-even
__device__ __forceinline__ short bfb(float f){
  unsigned u = __float_as_uint(f);
  u = u + 0x7fffu + ((u >> 16) & 1u);
  return (short)(u >> 16);
}

__device__ __forceinline__ bf16x8 cvt8(float4 a, float4 b){
  bf16x8 r;
  r[0]=bfb(a.x); r[1]=bfb(a.y); r[2]=bfb(a.z); r[3]=bfb(a.w);
  r[4]=bfb(b.x); r[5]=bfb(b.y); r[6]=bfb(b.z); r[7]=bfb(b.w);
  return r;
}

// Convert the 4 weight matrices to bf16 in ws.
__global__ __launch_bounds__(TB)
void k_convw(const float* __restrict__ a, const float* __restrict__ b,
             const float* __restrict__ c, const float* __restrict__ d,
             short* __restrict__ A, short* __restrict__ B,
             short* __restrict__ C, short* __restrict__ D){
  const int i = blockIdx.x*TB + threadIdx.x;
  if (i < 384*128){ A[i] = bfb(a[i]); B[i] = bfb(b[i]); }
  if (i < 128*128){ C[i] = bfb(c[i]); D[i] = bfb(d[i]); }
}

// FX[p][0:128] = x_p @ W_fx^T  (no bias; bfx added downstream), p = 0..nrows-1
__global__ __launch_bounds__(TB, 2)
void k_fx(const float* __restrict__ x, const short* __restrict__ Wfxb,
          float* __restrict__ FX, int nrows){
  const int tid = threadIdx.x;
  const int wave = tid >> 6, lane = tid & 63;
  const int l15 = lane & 15, lhi = lane >> 4;
  const int mrow = (blockIdx.x*4 + wave)*16;

  const int arow = min(mrow + l15, nrows - 1);
  bf16x8 ax[4];
  const float* rp = x + (size_t)arow*128;
  #pragma unroll
  for (int kf = 0; kf < 4; ++kf){
    const float4* p = (const float4*)(rp + kf*32 + lhi*8);
    ax[kf] = cvt8(p[0], p[1]);
  }
  f32x4 acc[8];
  #pragma unroll
  for (int t = 0; t < 8; ++t) acc[t] = (f32x4){0.f,0.f,0.f,0.f};
  #pragma unroll
  for (int t = 0; t < 8; ++t){
    const short* wr = Wfxb + (size_t)(t*16 + l15)*128 + lhi*8;
    #pragma unroll
    for (int kf = 0; kf < 4; ++kf){
      bf16x8 b = *(const bf16x8*)(wr + kf*32);
      acc[t] = __builtin_amdgcn_mfma_f32_16x16x32_bf16(ax[kf], b, acc[t], 0,0,0);
    }
  }
  #pragma unroll
  for (int tt = 0; tt < 8; ++tt){
    const int col = tt*16 + l15;
    #pragma unroll
    for (int r = 0; r < 4; ++r){
      const int row = mrow + lhi*4 + r;
      if (row < nrows) FX[(size_t)row*128 + col] = acc[tt][r];
    }
  }
}

// Unified per-level TreeLSTM step. Wave owns 16 nodes (2 complete parents).
//  iou = x@Wioux^T (+ hsum@Wiouh^T if HSin) + biases -> gates -> c,h
//  (if HSout) FH = h@Wfh^T; f = sigm(FH + bfh + bfx + FX[parent]);
//  parent reductions: fc_sum = sum f*c, h_sum = sum h  (8 siblings)
__global__ __launch_bounds__(TB, 2)
void k_node(const float* __restrict__ x, int xoff,
            const short* __restrict__ HSin, const float* __restrict__ FCin,
            const short* __restrict__ Wxb, const short* __restrict__ Whb,
            const short* __restrict__ Wfb,
            const float* __restrict__ bioux, const float* __restrict__ biouh,
            const float* __restrict__ bfx, const float* __restrict__ bfh,
            const float* __restrict__ FX, int poff,
            short* __restrict__ HSout, float* __restrict__ FCout,
            float* __restrict__ dout, int nnodes)
{
  __shared__ short hbuf[4][16*128];   // per-wave swizzled h tile (no barriers)
  const int tid = threadIdx.x;
  const int wave = tid >> 6, lane = tid & 63;
  const int l15 = lane & 15, lhi = lane >> 4;
  const int mrow = (blockIdx.x*4 + wave)*16;

  // ---- A fragments (row = lane&15, 8 contiguous k per lane) ----
  const int arow = min(mrow + l15, nnodes - 1);
  bf16x8 ax[4], ah[4];
  {
    const float* rp = x + (size_t)(xoff + arow)*128;
    #pragma unroll
    for (int kf = 0; kf < 4; ++kf){
      const float4* p = (const float4*)(rp + kf*32 + lhi*8);
      ax[kf] = cvt8(p[0], p[1]);
    }
  }
  if (HSin){
    const short* rp = HSin + (size_t)arow*128;
    #pragma unroll
    for (int kf = 0; kf < 4; ++kf)
      ah[kf] = *(const bf16x8*)(rp + kf*32 + lhi*8);
  }

  // ---- IOU GEMM: 24 n-tiles of 16 (i: 0..7, o: 8..15, u: 16..23) ----
  f32x4 acc[24];
  #pragma unroll
  for (int t = 0; t < 24; ++t) acc[t] = (f32x4){0.f,0.f,0.f,0.f};
  #pragma unroll
  for (int t = 0; t < 24; ++t){
    const short* wr = Wxb + (size_t)(t*16 + l15)*128 + lhi*8;
    #pragma unroll
    for (int kf = 0; kf < 4; ++kf){
      bf16x8 b = *(const bf16x8*)(wr + kf*32);
      acc[t] = __builtin_amdgcn_mfma_f32_16x16x32_bf16(ax[kf], b, acc[t], 0,0,0);
    }
  }
  if (HSin){
    #pragma unroll
    for (int t = 0; t < 24; ++t){
      const short* wr = Whb + (size_t)(t*16 + l15)*128 + lhi*8;
      #pragma unroll
      for (int kf = 0; kf < 4; ++kf){
        bf16x8 b = *(const bf16x8*)(wr + kf*32);
        acc[t] = __builtin_amdgcn_mfma_f32_16x16x32_bf16(ah[kf], b, acc[t], 0,0,0);
      }
    }
  }

  // ---- gates: C/D layout col = lane&15, row = (lane>>4)*4 + reg ----
  float cv[8][4];
  float hsum[8];
  #pragma unroll
  for (int tt = 0; tt < 8; ++tt){
    const int col = tt*16 + l15;
    const float bi = bioux[col]       + biouh[col];
    const float bo = bioux[128 + col] + biouh[128 + col];
    const float bu = bioux[256 + col] + biouh[256 + col];
    float hs = 0.f;
    #pragma unroll
    for (int r = 0; r < 4; ++r){
      const int row = lhi*4 + r;
      const int loc = min(mrow + row, nnodes - 1);
      const float fc = FCin ? FCin[(size_t)loc*128 + col] : 0.f;
      const float iv = acc[tt][r]      + bi;
      const float ov = acc[8 + tt][r]  + bo;
      const float uv = acc[16 + tt][r] + bu;
      const float c = sigm(iv)*tanhf(uv) + fc;
      const float h = sigm(ov)*tanhf(c);
      cv[tt][r] = c;
      hs += h;
      // swizzled LDS store: byte = row*256 + (2*col ^ (row<<4))
      const int byte = row*256 + ((col*2) ^ ((row & 15) << 4));
      *(short*)((char*)hbuf[wave] + byte) = bfb(h);
      if (dout && (mrow + row) == 0){   // root output
        dout[col] = c;
        dout[128 + col] = h;
      }
    }
    hsum[tt] = hs;
  }

  if (!HSout) return;   // level 0: done

  // ---- FH GEMM: A = h tile from swizzled LDS ----
  bf16x8 af[4];
  #pragma unroll
  for (int kf = 0; kf < 4; ++kf){
    const int byte = l15*256 + (((kf*32 + lhi*8)*2) ^ (l15 << 4));
    af[kf] = *(const bf16x8*)((const char*)hbuf[wave] + byte);
  }
  f32x4 facc[8];
  #pragma unroll
  for (int t = 0; t < 8; ++t) facc[t] = (f32x4){0.f,0.f,0.f,0.f};
  #pragma unroll
  for (int t = 0; t < 8; ++t){
    const short* wr = Wfb + (size_t)(t*16 + l15)*128 + lhi*8;
    #pragma unroll
    for (int kf = 0; kf < 4; ++kf){
      bf16x8 b = *(const bf16x8*)(wr + kf*32);
      facc[t] = __builtin_amdgcn_mfma_f32_16x16x32_bf16(af[kf], b, facc[t], 0,0,0);
    }
  }

  // ---- f, fc, and sibling reductions (8 rows per parent) ----
  const int pvalid0 = (mrow < nnodes);
  const int pvalid1 = (mrow + 8 < nnodes);
  #pragma unroll
  for (int tt = 0; tt < 8; ++tt){
    const int col = tt*16 + l15;
    const float bfv = bfh[col] + bfx[col];
    float fs = 0.f;
    #pragma unroll
    for (int r = 0; r < 4; ++r){
      const int row = lhi*4 + r;
      const int locp = min(mrow + row, nnodes - 1) >> 3;
      const float fxv = FX[(size_t)(poff + locp)*128 + col];
      const float f = sigm(facc[tt][r] + bfv + fxv);
      fs += f * cv[tt][r];
    }
    float hsv = hsum[tt];
    fs  += __shfl_xor(fs, 16);   // rows 0-3 + 4-7  /  8-11 + 12-15
    hsv += __shfl_xor(hsv, 16);
    if ((lhi & 1) == 0){
      const int pv = (lhi == 0) ? pvalid0 : pvalid1;
      if (pv){
        const int p = (mrow >> 3) + (lhi >> 1);
        FCout[(size_t)p*128 + col] = fs;
        HSout[(size_t)p*128 + col] = bfb(hsv);
      }
    }
  }
}

extern "C" void kernel_launch(void* const* d_in, const int* in_sizes, int n_in,
                              void* d_out, int out_size, void* d_ws, size_t ws_size,
                              hipStream_t stream)
{
  const float* x     = (const float*)d_in[0];
  const float* Wioux = (const float*)d_in[1];
  const float* bioux = (const float*)d_in[2];
  const float* Wiouh = (const float*)d_in[3];
  const float* biouh = (const float*)d_in[4];
  const float* Wfx   = (const float*)d_in[5];
  const float* bfx   = (const float*)d_in[6];
  const float* Wfh   = (const float*)d_in[7];
  const float* bfh   = (const float*)d_in[8];
  float* dout = (float*)d_out;

  static const int n_l[7]   = {1, 8, 64, 512, 4096, 32768, 262144};
  static const int off_l[7] = {0, 1, 9, 73, 585, 4681, 37449};

  char* base = (char*)d_ws;
  size_t off = 0;
  auto take = [&](size_t bytes)->char*{
    char* r = base + off;
    off = (off + bytes + 255) & ~(size_t)255;
    return r;
  };
  float* FX   = (float*)take((size_t)37449*128*4);
  float* FC0  = (float*)take((size_t)32768*128*4);
  float* FC1  = (float*)take((size_t)32768*128*4);
  short* HS0  = (short*)take((size_t)32768*128*2);
  short* HS1  = (short*)take((size_t)32768*128*2);
  short* WxB  = (short*)take((size_t)384*128*2);
  short* WhB  = (short*)take((size_t)384*128*2);
  short* WfxB = (short*)take((size_t)128*128*2);
  short* WfhB = (short*)take((size_t)128*128*2);
  if (off > ws_size) return;   // ~70 MB needed

  short* HS[2] = {HS0, HS1};
  float* FC[2] = {FC0, FC1};

  k_convw<<<192, TB, 0, stream>>>(Wioux, Wiouh, Wfx, Wfh, WxB, WhB, WfxB, WfhB);
  k_fx<<<(37449 + 63)/64, TB, 0, stream>>>(x, WfxB, FX, 37449);

  for (int l = 6; l >= 0; --l){
    const int n = n_l[l];
    const int grid = (n + 63)/64;
    k_node<<<grid, TB, 0, stream>>>(
      x, off_l[l],
      (l == 6) ? nullptr : HS[l & 1],
      (l == 6) ? nullptr : FC[l & 1],
      WxB, WhB, WfhB,
      bioux, biouh, bfx, bfh,
      FX, (l > 0) ? off_l[l-1] : 0,
      (l > 0) ? HS[(l & 1) ^ 1] : nullptr,
      (l > 0) ? FC[(l & 1) ^ 1] : nullptr,
      (l == 0) ? dout : nullptr, n);
  }
}

// Round 3
// 268.533 us; speedup vs baseline: 7.4701x; 2.3795x over previous
//
#include <hip/hip_runtime.h>
#include <hip/hip_bf16.h>

#define TB 256

typedef __attribute__((ext_vector_type(8))) short bf16x8;
typedef __attribute__((ext_vector_type(4))) float f32x4;

__device__ __forceinline__ float sigm(float v){ return 1.0f/(1.0f+__expf(-v)); }
__device__ __forceinline__ float tanh_fast(float v){
  float u = fminf(fmaxf(v, -15.f), 15.f);   // tanh saturates ~|9|; clamp avoids exp overflow
  float e = __expf(-2.f*u);
  return (1.f - e)/(1.f + e);
}

// f32 -> bf16 bits, round-to-nearest-even
__device__ __forceinline__ short bfb(float f){
  unsigned u = __float_as_uint(f);
  u = u + 0x7fffu + ((u >> 16) & 1u);
  return (short)(u >> 16);
}

__device__ __forceinline__ bf16x8 cvt8(float4 a, float4 b){
  bf16x8 r;
  r[0]=bfb(a.x); r[1]=bfb(a.y); r[2]=bfb(a.z); r[3]=bfb(a.w);
  r[4]=bfb(b.x); r[5]=bfb(b.y); r[6]=bfb(b.z); r[7]=bfb(b.w);
  return r;
}

// async global->LDS, 16B per lane; LDS dest is wave-uniform base (+lane*16 by HW)
#define GLD16(gp, lp) __builtin_amdgcn_global_load_lds( \
    (const __attribute__((address_space(1))) void*)(gp), \
    (__attribute__((address_space(3))) void*)(lp), 16, 0, 0)

// ---------------------------------------------------------------------------
// Weight prep: convert to bf16 AND permute into MFMA B-fragment order.
// Tile t = output cols [t*16,t*16+16); within tile, kf = k-block of 32;
// chunk element for lane l, j: W[t*16 + (l&15)][kf*32 + (l>>4)*8 + j].
// Flat short index: ((t*4 + kf)*64 + l)*8 + j  (tile = 2048 shorts = 4 KB).
// ---------------------------------------------------------------------------
__global__ __launch_bounds__(TB)
void k_prep(const float* __restrict__ Wioux, const float* __restrict__ Wiouh,
            const float* __restrict__ Wfx,   const float* __restrict__ Wfh,
            short* __restrict__ WxP, short* __restrict__ WhP,
            short* __restrict__ WfxP, short* __restrict__ WfhP){
  const int q = blockIdx.x*TB + threadIdx.x;        // one bf16x8 chunk per thread
  const int t = q >> 8, rem = q & 255;
  const int kf = rem >> 6, lane = rem & 63;
  const int row = t*16 + (lane & 15);
  const int col = kf*32 + (lane >> 4)*8;
  const size_t src = (size_t)row*128 + col;
  if (q < 6144){                                     // 24 tiles (384x128)
    const float4* p = (const float4*)(Wioux + src);
    *(bf16x8*)(WxP + (size_t)q*8) = cvt8(p[0], p[1]);
    const float4* p2 = (const float4*)(Wiouh + src);
    *(bf16x8*)(WhP + (size_t)q*8) = cvt8(p2[0], p2[1]);
  }
  if (q < 2048){                                     // 8 tiles (128x128)
    const float4* p = (const float4*)(Wfx + src);
    *(bf16x8*)(WfxP + (size_t)q*8) = cvt8(p[0], p[1]);
    const float4* p2 = (const float4*)(Wfh + src);
    *(bf16x8*)(WfhP + (size_t)q*8) = cvt8(p2[0], p2[1]);
  }
}

// FX[p] = x_p @ W_fx^T  (no bias), for all 37449 parents. WfxP (32 KB) is
// L1-resident; fragment-order reads are fully coalesced (1 KB/wave-instr).
__global__ __launch_bounds__(TB, 2)
void k_fx(const float* __restrict__ x, const short* __restrict__ WfxP,
          float* __restrict__ FX, int nrows){
  const int tid = threadIdx.x, wave = tid >> 6, lane = tid & 63;
  const int l15 = lane & 15, lhi = lane >> 4;
  const int mrow = (blockIdx.x*4 + wave)*16;
  const int arow = min(mrow + l15, nrows - 1);
  bf16x8 ax[4];
  const float* rp = x + (size_t)arow*128;
  #pragma unroll
  for (int kf = 0; kf < 4; ++kf){
    const float4* p = (const float4*)(rp + kf*32 + lhi*8);
    ax[kf] = cvt8(p[0], p[1]);
  }
  #pragma unroll
  for (int t = 0; t < 8; ++t){
    f32x4 acc = {0.f,0.f,0.f,0.f};
    #pragma unroll
    for (int kf = 0; kf < 4; ++kf){
      bf16x8 b = *(const bf16x8*)(WfxP + ((size_t)(t*4 + kf)*64 + lane)*8);
      acc = __builtin_amdgcn_mfma_f32_16x16x32_bf16(ax[kf], b, acc, 0,0,0);
    }
    const int col = t*16 + l15;
    #pragma unroll
    for (int r = 0; r < 4; ++r){
      const int row = mrow + lhi*4 + r;
      if (row < nrows) FX[(size_t)row*128 + col] = acc[r];
    }
  }
}

// ---------------------------------------------------------------------------
// Unified per-level TreeLSTM step, block = 4 waves x 16 rows = 64 nodes.
// Weights staged group-wise into LDS (global_load_lds, linear frag order).
// Group tt: output cols [tt*16,tt*16+16) of i (tile tt), o (8+tt), u (16+tt).
// ---------------------------------------------------------------------------
__global__ __launch_bounds__(TB, 3)
void k_node(const float* __restrict__ x, int xoff,
            const short* __restrict__ HSin, const float* __restrict__ FCin,
            const short* __restrict__ WxP, const short* __restrict__ WhP,
            const short* __restrict__ WfhP,
            const float* __restrict__ bioux, const float* __restrict__ biouh,
            const float* __restrict__ bfx, const float* __restrict__ bfh,
            const float* __restrict__ FX, int poff,
            short* __restrict__ HSout, float* __restrict__ FCout,
            float* __restrict__ dout, int nnodes)
{
  __shared__ short wbuf[6*2048];      // 24 KB: up to 6 staged 16x128 bf16 tiles
  __shared__ short hbuf[4][2048];     // 4 KB/wave: swizzled h tile for FH
  const int tid = threadIdx.x;
  const int wave = tid >> 6, lane = tid & 63;
  const int l15 = lane & 15, lhi = lane >> 4;
  const int mrow = (blockIdx.x*4 + wave)*16;
  const int arow = min(mrow + l15, nnodes - 1);

  // ---- A fragments: x rows (cvt f32->bf16), h_sum rows (bf16) ----
  bf16x8 ax[4], ah[4];
  {
    const float* rp = x + (size_t)(xoff + arow)*128;
    #pragma unroll
    for (int kf = 0; kf < 4; ++kf){
      const float4* p = (const float4*)(rp + kf*32 + lhi*8);
      ax[kf] = cvt8(p[0], p[1]);
    }
  }
  if (HSin){
    const short* rp = HSin + (size_t)arow*128;
    #pragma unroll
    for (int kf = 0; kf < 4; ++kf)
      ah[kf] = *(const bf16x8*)(rp + kf*32 + lhi*8);
  }

  float cv[8][4];       // c values (this wave's 16 rows x its 16-col group)
  float hsumv[8];       // per-thread partial h sums

  #pragma unroll
  for (int tt = 0; tt < 8; ++tt){
    __syncthreads();    // previous group done reading wbuf
    // stage Wx tiles {tt, 8+tt, 16+tt} -> slots 0..2 (+ Wh -> slots 3..5)
    GLD16(WxP + (size_t)( tt     *2048) + wave*512 + lane*8, wbuf + 0*2048 + wave*512);
    GLD16(WxP + (size_t)((8+tt)  *2048) + wave*512 + lane*8, wbuf + 1*2048 + wave*512);
    GLD16(WxP + (size_t)((16+tt) *2048) + wave*512 + lane*8, wbuf + 2*2048 + wave*512);
    if (HSin){
      GLD16(WhP + (size_t)( tt     *2048) + wave*512 + lane*8, wbuf + 3*2048 + wave*512);
      GLD16(WhP + (size_t)((8+tt)  *2048) + wave*512 + lane*8, wbuf + 4*2048 + wave*512);
      GLD16(WhP + (size_t)((16+tt) *2048) + wave*512 + lane*8, wbuf + 5*2048 + wave*512);
    }
    __syncthreads();    // staged data visible

    f32x4 ai = {0.f,0.f,0.f,0.f}, ao = ai, au = ai;
    #pragma unroll
    for (int kf = 0; kf < 4; ++kf){
      bf16x8 b0 = *(const bf16x8*)(wbuf + 0*2048 + kf*512 + lane*8);
      bf16x8 b1 = *(const bf16x8*)(wbuf + 1*2048 + kf*512 + lane*8);
      bf16x8 b2 = *(const bf16x8*)(wbuf + 2*2048 + kf*512 + lane*8);
      ai = __builtin_amdgcn_mfma_f32_16x16x32_bf16(ax[kf], b0, ai, 0,0,0);
      ao = __builtin_amdgcn_mfma_f32_16x16x32_bf16(ax[kf], b1, ao, 0,0,0);
      au = __builtin_amdgcn_mfma_f32_16x16x32_bf16(ax[kf], b2, au, 0,0,0);
    }
    if (HSin){
      #pragma unroll
      for (int kf = 0; kf < 4; ++kf){
        bf16x8 b0 = *(const bf16x8*)(wbuf + 3*2048 + kf*512 + lane*8);
        bf16x8 b1 = *(const bf16x8*)(wbuf + 4*2048 + kf*512 + lane*8);
        bf16x8 b2 = *(const bf16x8*)(wbuf + 5*2048 + kf*512 + lane*8);
        ai = __builtin_amdgcn_mfma_f32_16x16x32_bf16(ah[kf], b0, ai, 0,0,0);
        ao = __builtin_amdgcn_mfma_f32_16x16x32_bf16(ah[kf], b1, ao, 0,0,0);
        au = __builtin_amdgcn_mfma_f32_16x16x32_bf16(ah[kf], b2, au, 0,0,0);
      }
    }

    // ---- gates for this 16-col group (C/D: col=lane&15, row=lhi*4+r) ----
    const int col = tt*16 + l15;
    const float bi = bioux[col]       + biouh[col];
    const float bo = bioux[128 + col] + biouh[128 + col];
    const float bu = bioux[256 + col] + biouh[256 + col];
    float hs = 0.f;
    #pragma unroll
    for (int r = 0; r < 4; ++r){
      const int row = lhi*4 + r;
      const int loc = min(mrow + row, nnodes - 1);
      const float fc = FCin ? FCin[(size_t)loc*128 + col] : 0.f;
      const float c = sigm(ai[r] + bi) * tanh_fast(au[r] + bu) + fc;
      const float h = sigm(ao[r] + bo) * tanh_fast(c);
      cv[tt][r] = c;
      hs += h;
      const int byte = row*256 + ((col*2) ^ ((row & 15) << 4));   // swizzled
      *(short*)((char*)hbuf[wave] + byte) = bfb(h);
      if (dout && (mrow + row) == 0){ dout[col] = c; dout[128 + col] = h; }
    }
    hsumv[tt] = hs;
  }

  if (!HSout) return;   // root level: done (uniform exit, no barriers skipped mid-wait)

  // ---- FH = h @ W_fh^T ; f-gate ; sibling reductions ----
  bf16x8 af[4];
  #pragma unroll
  for (int kf = 0; kf < 4; ++kf){
    const int byte = l15*256 + (((kf*32 + lhi*8)*2) ^ (l15 << 4));
    af[kf] = *(const bf16x8*)((const char*)hbuf[wave] + byte);
  }

  float fsv[8];
  #pragma unroll
  for (int fg = 0; fg < 2; ++fg){
    __syncthreads();
    #pragma unroll
    for (int t2 = 0; t2 < 4; ++t2)
      GLD16(WfhP + (size_t)(fg*4 + t2)*2048 + wave*512 + lane*8, wbuf + t2*2048 + wave*512);
    __syncthreads();
    #pragma unroll
    for (int t2 = 0; t2 < 4; ++t2){
      f32x4 fa = {0.f,0.f,0.f,0.f};
      #pragma unroll
      for (int kf = 0; kf < 4; ++kf){
        bf16x8 b = *(const bf16x8*)(wbuf + t2*2048 + kf*512 + lane*8);
        fa = __builtin_amdgcn_mfma_f32_16x16x32_bf16(af[kf], b, fa, 0,0,0);
      }
      const int tt = fg*4 + t2;
      const int col = tt*16 + l15;
      const float bfv = bfh[col] + bfx[col];
      float fs = 0.f;
      #pragma unroll
      for (int r = 0; r < 4; ++r){
        const int locp = min(mrow + lhi*4 + r, nnodes - 1) >> 3;
        const float f = sigm(fa[r] + bfv + FX[(size_t)(poff + locp)*128 + col]);
        fs += f * cv[tt][r];
      }
      fsv[tt] = fs;
    }
  }

  const int pv0 = (mrow < nnodes), pv1 = (mrow + 8 < nnodes);
  #pragma unroll
  for (int tt = 0; tt < 8; ++tt){
    const int col = tt*16 + l15;
    const float fs = fsv[tt]   + __shfl_xor(fsv[tt], 16);
    const float hs = hsumv[tt] + __shfl_xor(hsumv[tt], 16);
    if ((lhi & 1) == 0){
      const int pv = (lhi == 0) ? pv0 : pv1;
      if (pv){
        const int p = (mrow >> 3) + (lhi >> 1);
        FCout[(size_t)p*128 + col] = fs;
        HSout[(size_t)p*128 + col] = bfb(hs);
      }
    }
  }
}

extern "C" void kernel_launch(void* const* d_in, const int* in_sizes, int n_in,
                              void* d_out, int out_size, void* d_ws, size_t ws_size,
                              hipStream_t stream)
{
  const float* x     = (const float*)d_in[0];
  const float* Wioux = (const float*)d_in[1];
  const float* bioux = (const float*)d_in[2];
  const float* Wiouh = (const float*)d_in[3];
  const float* biouh = (const float*)d_in[4];
  const float* Wfx   = (const float*)d_in[5];
  const float* bfx   = (const float*)d_in[6];
  const float* Wfh   = (const float*)d_in[7];
  const float* bfh   = (const float*)d_in[8];
  float* dout = (float*)d_out;

  static const int n_l[7]   = {1, 8, 64, 512, 4096, 32768, 262144};
  static const int off_l[7] = {0, 1, 9, 73, 585, 4681, 37449};

  char* base = (char*)d_ws;
  size_t off = 0;
  auto take = [&](size_t bytes)->char*{
    char* r = base + off;
    off = (off + bytes + 255) & ~(size_t)255;
    return r;
  };
  float* FX   = (float*)take((size_t)37449*128*4);
  float* FC0  = (float*)take((size_t)32768*128*4);
  float* FC1  = (float*)take((size_t)32768*128*4);
  short* HS0  = (short*)take((size_t)32768*128*2);
  short* HS1  = (short*)take((size_t)32768*128*2);
  short* WxP  = (short*)take((size_t)24*2048*2);
  short* WhP  = (short*)take((size_t)24*2048*2);
  short* WfxP = (short*)take((size_t)8*2048*2);
  short* WfhP = (short*)take((size_t)8*2048*2);
  if (off > ws_size) return;   // ~70 MB needed

  short* HS[2] = {HS0, HS1};
  float* FC[2] = {FC0, FC1};

  k_prep<<<24, TB, 0, stream>>>(Wioux, Wiouh, Wfx, Wfh, WxP, WhP, WfxP, WfhP);
  k_fx<<<(37449 + 63)/64, TB, 0, stream>>>(x, WfxP, FX, 37449);

  for (int l = 6; l >= 0; --l){
    const int n = n_l[l];
    const int grid = (n + 63)/64;
    k_node<<<grid, TB, 0, stream>>>(
      x, off_l[l],
      (l == 6) ? nullptr : HS[l & 1],
      (l == 6) ? nullptr : FC[l & 1],
      WxP, WhP, WfhP,
      bioux, biouh, bfx, bfh,
      FX, (l > 0) ? off_l[l-1] : 0,
      (l > 0) ? HS[(l & 1) ^ 1] : nullptr,
      (l > 0) ? FC[(l & 1) ^ 1] : nullptr,
      (l == 0) ? dout : nullptr, n);
  }
}

// Round 4
// 193.458 us; speedup vs baseline: 10.3690x; 1.3881x over previous
//
#include <hip/hip_runtime.h>
#include <hip/hip_bf16.h>

#define TB 256
#define LOG2E  1.44269504088896f
#define LOG2E2 2.88539008177793f

typedef __attribute__((ext_vector_type(8))) short bf16x8;
typedef __attribute__((ext_vector_type(4))) float f32x4;

// f32 -> bf16 bits, round-to-nearest-even
__device__ __forceinline__ short bfb(float f){
  unsigned u = __float_as_uint(f);
  u = u + 0x7fffu + ((u >> 16) & 1u);
  return (short)(u >> 16);
}
__device__ __forceinline__ bf16x8 cvt8(float4 a, float4 b){
  bf16x8 r;
  r[0]=bfb(a.x); r[1]=bfb(a.y); r[2]=bfb(a.z); r[3]=bfb(a.w);
  r[4]=bfb(b.x); r[5]=bfb(b.y); r[6]=bfb(b.z); r[7]=bfb(b.w);
  return r;
}
// sigm(z) with pre-scaled arg: s = rcp(1 + exp2(arg)), arg = -log2e*z
__device__ __forceinline__ float sig2(float arg){
  return __builtin_amdgcn_rcpf(1.f + __builtin_amdgcn_exp2f(arg));
}
// tanh(z) with arg = 2*log2e*z:  1 - 2/(1+exp2(arg))
__device__ __forceinline__ float tanh2(float arg){
  return 1.f - 2.f*__builtin_amdgcn_rcpf(1.f + __builtin_amdgcn_exp2f(arg));
}

// async global->LDS, 16B per lane; LDS dest is wave-uniform base (+lane*16 by HW)
#define GLD16(gp, lp) __builtin_amdgcn_global_load_lds( \
    (const __attribute__((address_space(1))) void*)(gp), \
    (__attribute__((address_space(3))) void*)(lp), 16, 0, 0)

// ---------------------------------------------------------------------------
// k_prep: bf16-convert + permute weights into MFMA B-fragment order.
// Fragment chunk for (tile t, kf, lane l): W[t*16+(l&15)][kf*32+(l>>4)*8 + 0..7]
// WxG/WhG: GROUP-major: group tt (0..7) = tiles {tt, 8+tt, 16+tt} contiguous
//   (6144 shorts = 12 KB per group). WfxP/WfhP: tile-major (2048 shorts/tile).
// biasS[384]: pre-scaled gate biases.
// ---------------------------------------------------------------------------
__global__ __launch_bounds__(TB)
void k_prep(const float* __restrict__ Wioux, const float* __restrict__ Wiouh,
            const float* __restrict__ Wfx,   const float* __restrict__ Wfh,
            const float* __restrict__ bioux, const float* __restrict__ biouh,
            short* __restrict__ WxG, short* __restrict__ WhG,
            short* __restrict__ WfxP, short* __restrict__ WfhP,
            float* __restrict__ biasS){
  const int q = blockIdx.x*TB + threadIdx.x;
  const int t = q >> 8, rem = q & 255;
  const int kf = rem >> 6, lane = rem & 63;
  const int row = t*16 + (lane & 15);
  const int col = kf*32 + (lane >> 4)*8;
  const size_t src = (size_t)row*128 + col;
  if (q < 6144){                       // 24 tiles of Wioux/Wiouh
    const int g = t & 7, kind = t >> 3;
    const size_t dst = ((size_t)(g*3 + kind)*4 + kf)*512 + (size_t)lane*8;
    const float4* p  = (const float4*)(Wioux + src);
    *(bf16x8*)(WxG + dst) = cvt8(p[0], p[1]);
    const float4* p2 = (const float4*)(Wiouh + src);
    *(bf16x8*)(WhG + dst) = cvt8(p2[0], p2[1]);
  }
  if (q < 2048){                       // 8 tiles of Wfx/Wfh
    const size_t dst = ((size_t)t*4 + kf)*512 + (size_t)lane*8;
    const float4* p  = (const float4*)(Wfx + src);
    *(bf16x8*)(WfxP + dst) = cvt8(p[0], p[1]);
    const float4* p2 = (const float4*)(Wfh + src);
    *(bf16x8*)(WfhP + dst) = cvt8(p2[0], p2[1]);
  }
  if (q < 384){
    const float s = (q < 256) ? -LOG2E : LOG2E2;
    biasS[q] = s*(bioux[q] + biouh[q]);
  }
}

// FXS[p][c] = -log2e * (x_p @ W_fx^T + bfx + bfh)[c]  for all internal nodes
__global__ __launch_bounds__(TB, 4)
void k_fx(const float* __restrict__ x, const short* __restrict__ WfxP,
          const float* __restrict__ bfx, const float* __restrict__ bfh,
          float* __restrict__ FXS, int nrows){
  const int tid = threadIdx.x, wave = tid >> 6, lane = tid & 63;
  const int l15 = lane & 15, lhi = lane >> 4;
  const int mrow = (blockIdx.x*4 + wave)*16;
  const int arow = min(mrow + l15, nrows - 1);
  bf16x8 ax[4];
  const float* rp = x + (size_t)arow*128;
  #pragma unroll
  for (int kf = 0; kf < 4; ++kf){
    const float4* p = (const float4*)(rp + kf*32 + lhi*8);
    ax[kf] = cvt8(p[0], p[1]);
  }
  #pragma unroll
  for (int t = 0; t < 8; ++t){
    f32x4 acc = {0.f,0.f,0.f,0.f};
    #pragma unroll
    for (int kf = 0; kf < 4; ++kf){
      bf16x8 b = *(const bf16x8*)(WfxP + ((size_t)(t*4 + kf)*64 + lane)*8);
      acc = __builtin_amdgcn_mfma_f32_16x16x32_bf16(ax[kf], b, acc, 0,0,0);
    }
    const int col = t*16 + l15;
    const float bc = bfx[col] + bfh[col];
    #pragma unroll
    for (int r = 0; r < 4; ++r){
      const int row = mrow + lhi*4 + r;
      if (row < nrows) FXS[(size_t)row*128 + col] = -LOG2E*(acc[r] + bc);
    }
  }
}

// ---------------------------------------------------------------------------
// k_leaf: level-6 nodes. 4 waves x 16 rows. IOU weights staged group-wise
// (double-buffered prefetch); FH weights direct from global (32KB, L1-hot).
// ---------------------------------------------------------------------------
__global__ __launch_bounds__(TB, 4)
void k_leaf(const float* __restrict__ x, int xoff,
            const short* __restrict__ WxG, const short* __restrict__ WfhP,
            const float* __restrict__ biasS, const float* __restrict__ FXS,
            int poff, short* __restrict__ HSout, float* __restrict__ FCout)
{
  __shared__ __align__(16) short wbuf[2][6144];   // 2 x 12 KB IOU group
  __shared__ __align__(16) short hbuf[4][2048];   // per-wave swizzled h tile
  const int tid = threadIdx.x;
  const int wave = tid >> 6, lane = tid & 63;
  const int l15 = lane & 15, lhi = lane >> 4;
  const int mrow = (blockIdx.x*4 + wave)*16;      // exact: 262144 % 64 == 0

  // A fragments (x rows -> bf16)
  bf16x8 ax[4];
  {
    const float* rp = x + (size_t)(xoff + mrow + l15)*128;
    #pragma unroll
    for (int kf = 0; kf < 4; ++kf){
      const float4* p = (const float4*)(rp + kf*32 + lhi*8);
      ax[kf] = cvt8(p[0], p[1]);
    }
  }

  // stage IOU group g into buffer b (3 chunks of 1KB per wave)
  #define STAGE_L(g, b) { \
    _Pragma("unroll") \
    for (int c = 0; c < 3; ++c){ \
      const int ch = c*4 + wave; \
      GLD16(WxG + (size_t)(g)*6144 + ch*512 + lane*8, &wbuf[b][ch*512]); \
    } }

  STAGE_L(0, 0);

  float cv[8][4];
  const int colb = l15*2;
  const int p = (mrow >> 3) + (lhi >> 1);            // this thread's parent
  const float* fxp = FXS + (size_t)(poff + p)*128 + l15;

  #pragma unroll
  for (int tt = 0; tt < 8; ++tt){
    __syncthreads();                    // drains stage(tt) [vmcnt before barrier]
    if (tt < 7) STAGE_L(tt+1, (tt+1)&1);
    const short* wb = wbuf[tt & 1];

    f32x4 ai = {0.f,0.f,0.f,0.f}, ao = ai, au = ai;
    #pragma unroll
    for (int kf = 0; kf < 4; ++kf){
      bf16x8 bi = *(const bf16x8*)(wb + 0*2048 + kf*512 + lane*8);
      bf16x8 bo = *(const bf16x8*)(wb + 1*2048 + kf*512 + lane*8);
      bf16x8 bu = *(const bf16x8*)(wb + 2*2048 + kf*512 + lane*8);
      ai = __builtin_amdgcn_mfma_f32_16x16x32_bf16(ax[kf], bi, ai, 0,0,0);
      ao = __builtin_amdgcn_mfma_f32_16x16x32_bf16(ax[kf], bo, ao, 0,0,0);
      au = __builtin_amdgcn_mfma_f32_16x16x32_bf16(ax[kf], bu, au, 0,0,0);
    }

    const int col = tt*16 + l15;
    const float bis = biasS[col], bos = biasS[128 + col], bus = biasS[256 + col];
    const int colx = colb + tt*32;
    float hs = 0.f;
    #pragma unroll
    for (int r = 0; r < 4; ++r){
      const int row = lhi*4 + r;
      const float iv = sig2 (__builtin_fmaf(ai[r], -LOG2E, bis));
      const float uv = tanh2(__builtin_fmaf(au[r],  LOG2E2, bus));
      const float ov = sig2 (__builtin_fmaf(ao[r], -LOG2E, bos));
      const float c  = iv*uv;                        // leaf: fc_sum = 0
      const float h  = ov*tanh2(LOG2E2*c);
      cv[tt][r] = c;
      hs += h;
      const int byte = row*256 + (colx ^ (row << 4));
      *(short*)((char*)hbuf[wave] + byte) = bfb(h);
    }
    hs += __shfl_xor(hs, 16);
    if ((lhi & 1) == 0)
      HSout[(size_t)p*128 + col] = bfb(hs);
  }

  // ---- FH = h @ W_fh^T (B direct from global), f-gate, fc reduction ----
  bf16x8 af[4];
  #pragma unroll
  for (int kf = 0; kf < 4; ++kf){
    const int byte = l15*256 + (((kf*32 + lhi*8)*2) ^ (l15 << 4));
    af[kf] = *(const bf16x8*)((const char*)hbuf[wave] + byte);
  }
  #pragma unroll
  for (int t2 = 0; t2 < 8; ++t2){
    f32x4 fa = {0.f,0.f,0.f,0.f};
    #pragma unroll
    for (int kf = 0; kf < 4; ++kf){
      bf16x8 b = *(const bf16x8*)(WfhP + ((size_t)(t2*4 + kf)*64 + lane)*8);
      fa = __builtin_amdgcn_mfma_f32_16x16x32_bf16(af[kf], b, fa, 0,0,0);
    }
    const float fxv = fxp[t2*16];                    // = -log2e*(FX+bfx+bfh)
    float fs = 0.f;
    #pragma unroll
    for (int r = 0; r < 4; ++r){
      const float f = sig2(__builtin_fmaf(fa[r], -LOG2E, fxv));
      fs += f * cv[t2][r];
    }
    fs += __shfl_xor(fs, 16);
    if ((lhi & 1) == 0)
      FCout[(size_t)p*128 + t2*16 + l15] = fs;
  }
  #undef STAGE_L
}

// ---------------------------------------------------------------------------
// k_node: internal levels (have HSin/FCin). 6-tile groups (Wx+Wh), dbuf.
// ---------------------------------------------------------------------------
__global__ __launch_bounds__(TB, 2)
void k_node(const float* __restrict__ x, int xoff,
            const short* __restrict__ HSin, const float* __restrict__ FCin,
            const short* __restrict__ WxG, const short* __restrict__ WhG,
            const short* __restrict__ WfhP,
            const float* __restrict__ biasS, const float* __restrict__ FXS,
            int poff, short* __restrict__ HSout, float* __restrict__ FCout,
            float* __restrict__ dout, int nnodes)
{
  __shared__ __align__(16) short wbuf[2][12288];  // 2 x 24 KB (Wx|Wh group)
  __shared__ __align__(16) short hbuf[4][2048];
  const int tid = threadIdx.x;
  const int wave = tid >> 6, lane = tid & 63;
  const int l15 = lane & 15, lhi = lane >> 4;
  const int mrow = (blockIdx.x*4 + wave)*16;
  const int arow = min(mrow + l15, nnodes - 1);

  bf16x8 ax[4], ah[4];
  {
    const float* rp = x + (size_t)(xoff + arow)*128;
    #pragma unroll
    for (int kf = 0; kf < 4; ++kf){
      const float4* p = (const float4*)(rp + kf*32 + lhi*8);
      ax[kf] = cvt8(p[0], p[1]);
    }
    const short* hp = HSin + (size_t)arow*128;
    #pragma unroll
    for (int kf = 0; kf < 4; ++kf)
      ah[kf] = *(const bf16x8*)(hp + kf*32 + lhi*8);
  }

  #define STAGE_N(g, b) { \
    _Pragma("unroll") \
    for (int c = 0; c < 3; ++c){ \
      const int ch = c*4 + wave; \
      GLD16(WxG + (size_t)(g)*6144 + ch*512 + lane*8, &wbuf[b][ch*512]); \
      GLD16(WhG + (size_t)(g)*6144 + ch*512 + lane*8, &wbuf[b][6144 + ch*512]); \
    } }

  STAGE_N(0, 0);

  float cv[8][4];
  const int colb = l15*2;
  const int p = (min(mrow, nnodes - 1) >> 3) + (lhi >> 1);
  const float* fxp = FXS + (size_t)(poff + min(p, (nnodes - 1) >> 3))*128 + l15;

  #pragma unroll
  for (int tt = 0; tt < 8; ++tt){
    __syncthreads();
    if (tt < 7) STAGE_N(tt+1, (tt+1)&1);
    const short* wb = wbuf[tt & 1];

    f32x4 ai = {0.f,0.f,0.f,0.f}, ao = ai, au = ai;
    #pragma unroll
    for (int kf = 0; kf < 4; ++kf){
      bf16x8 bi = *(const bf16x8*)(wb + 0*2048 + kf*512 + lane*8);
      bf16x8 bo = *(const bf16x8*)(wb + 1*2048 + kf*512 + lane*8);
      bf16x8 bu = *(const bf16x8*)(wb + 2*2048 + kf*512 + lane*8);
      ai = __builtin_amdgcn_mfma_f32_16x16x32_bf16(ax[kf], bi, ai, 0,0,0);
      ao = __builtin_amdgcn_mfma_f32_16x16x32_bf16(ax[kf], bo, ao, 0,0,0);
      au = __builtin_amdgcn_mfma_f32_16x16x32_bf16(ax[kf], bu, au, 0,0,0);
    }
    #pragma unroll
    for (int kf = 0; kf < 4; ++kf){
      bf16x8 bi = *(const bf16x8*)(wb + 6144 + 0*2048 + kf*512 + lane*8);
      bf16x8 bo = *(const bf16x8*)(wb + 6144 + 1*2048 + kf*512 + lane*8);
      bf16x8 bu = *(const bf16x8*)(wb + 6144 + 2*2048 + kf*512 + lane*8);
      ai = __builtin_amdgcn_mfma_f32_16x16x32_bf16(ah[kf], bi, ai, 0,0,0);
      ao = __builtin_amdgcn_mfma_f32_16x16x32_bf16(ah[kf], bo, ao, 0,0,0);
      au = __builtin_amdgcn_mfma_f32_16x16x32_bf16(ah[kf], bu, au, 0,0,0);
    }

    const int col = tt*16 + l15;
    const float bis = biasS[col], bos = biasS[128 + col], bus = biasS[256 + col];
    const int colx = colb + tt*32;
    float hs = 0.f;
    #pragma unroll
    for (int r = 0; r < 4; ++r){
      const int row = lhi*4 + r;
      const int loc = min(mrow + row, nnodes - 1);
      const float fc = FCin[(size_t)loc*128 + col];
      const float iv = sig2 (__builtin_fmaf(ai[r], -LOG2E, bis));
      const float uv = tanh2(__builtin_fmaf(au[r],  LOG2E2, bus));
      const float ov = sig2 (__builtin_fmaf(ao[r], -LOG2E, bos));
      const float c  = __builtin_fmaf(iv, uv, fc);
      const float h  = ov*tanh2(LOG2E2*c);
      cv[tt][r] = c;
      hs += h;
      const int byte = row*256 + (colx ^ (row << 4));
      *(short*)((char*)hbuf[wave] + byte) = bfb(h);
      if (dout && (mrow + row) == 0){ dout[col] = c; dout[128 + col] = h; }
    }
    if (HSout){
      hs += __shfl_xor(hs, 16);
      if ((lhi & 1) == 0){
        const int pv = (lhi == 0) ? (mrow < nnodes) : (mrow + 8 < nnodes);
        if (pv) HSout[(size_t)p*128 + col] = bfb(hs);
      }
    }
  }

  if (!HSout) return;   // root

  bf16x8 af[4];
  #pragma unroll
  for (int kf = 0; kf < 4; ++kf){
    const int byte = l15*256 + (((kf*32 + lhi*8)*2) ^ (l15 << 4));
    af[kf] = *(const bf16x8*)((const char*)hbuf[wave] + byte);
  }
  #pragma unroll
  for (int t2 = 0; t2 < 8; ++t2){
    f32x4 fa = {0.f,0.f,0.f,0.f};
    #pragma unroll
    for (int kf = 0; kf < 4; ++kf){
      bf16x8 b = *(const bf16x8*)(WfhP + ((size_t)(t2*4 + kf)*64 + lane)*8);
      fa = __builtin_amdgcn_mfma_f32_16x16x32_bf16(af[kf], b, fa, 0,0,0);
    }
    const float fxv = fxp[t2*16];
    float fs = 0.f;
    #pragma unroll
    for (int r = 0; r < 4; ++r){
      const float f = sig2(__builtin_fmaf(fa[r], -LOG2E, fxv));
      fs += f * cv[t2][r];
    }
    fs += __shfl_xor(fs, 16);
    if ((lhi & 1) == 0){
      const int pv = (lhi == 0) ? (mrow < nnodes) : (mrow + 8 < nnodes);
      if (pv) FCout[(size_t)p*128 + t2*16 + l15] = fs;
    }
  }
  #undef STAGE_N
}

extern "C" void kernel_launch(void* const* d_in, const int* in_sizes, int n_in,
                              void* d_out, int out_size, void* d_ws, size_t ws_size,
                              hipStream_t stream)
{
  const float* x     = (const float*)d_in[0];
  const float* Wioux = (const float*)d_in[1];
  const float* bioux = (const float*)d_in[2];
  const float* Wiouh = (const float*)d_in[3];
  const float* biouh = (const float*)d_in[4];
  const float* Wfx   = (const float*)d_in[5];
  const float* bfx   = (const float*)d_in[6];
  const float* Wfh   = (const float*)d_in[7];
  const float* bfh   = (const float*)d_in[8];
  float* dout = (float*)d_out;

  static const int n_l[7]   = {1, 8, 64, 512, 4096, 32768, 262144};
  static const int off_l[7] = {0, 1, 9, 73, 585, 4681, 37449};

  char* base = (char*)d_ws;
  size_t off = 0;
  auto take = [&](size_t bytes)->char*{
    char* r = base + off;
    off = (off + bytes + 255) & ~(size_t)255;
    return r;
  };
  float* FXS  = (float*)take((size_t)37449*128*4);
  float* FC0  = (float*)take((size_t)32768*128*4);
  float* FC1  = (float*)take((size_t)32768*128*4);
  short* HS0  = (short*)take((size_t)32768*128*2);
  short* HS1  = (short*)take((size_t)32768*128*2);
  short* WxG  = (short*)take((size_t)24*2048*2);
  short* WhG  = (short*)take((size_t)24*2048*2);
  short* WfxP = (short*)take((size_t)8*2048*2);
  short* WfhP = (short*)take((size_t)8*2048*2);
  float* biasS= (float*)take((size_t)384*4);
  if (off > ws_size) return;

  short* HS[2] = {HS0, HS1};
  float* FC[2] = {FC0, FC1};

  k_prep<<<24, TB, 0, stream>>>(Wioux, Wiouh, Wfx, Wfh, bioux, biouh,
                                WxG, WhG, WfxP, WfhP, biasS);
  k_fx<<<(37449 + 63)/64, TB, 0, stream>>>(x, WfxP, bfx, bfh, FXS, 37449);

  // leaf level (l=6): writes HS1/FC1 (matches l=5 reading HS[5&1]=HS1)
  k_leaf<<<262144/64, TB, 0, stream>>>(x, off_l[6], WxG, WfhP, biasS, FXS,
                                       off_l[5], HS1, FC1);

  for (int l = 5; l >= 0; --l){
    const int n = n_l[l];
    const int grid = (n + 63)/64;
    k_node<<<grid, TB, 0, stream>>>(
      x, off_l[l], HS[l & 1], FC[l & 1],
      WxG, WhG, WfhP, biasS, FXS,
      (l > 0) ? off_l[l-1] : 0,
      (l > 0) ? HS[(l & 1) ^ 1] : nullptr,
      (l > 0) ? FC[(l & 1) ^ 1] : nullptr,
      (l == 0) ? dout : nullptr, n);
  }
}